// Round 1
// baseline (215.710 us; speedup 1.0000x reference)
//
#include <hip/hip_runtime.h>
#include <hip/hip_bf16.h>

#define S_LEN 2048
#define HDIM  1024
#define NHEADS 16
#define HD    64
#define QKV_STRIDE (S_LEN * 2 * HDIM)   // 4194304 elements per tensor

typedef __attribute__((ext_vector_type(8))) short short8;
typedef __attribute__((ext_vector_type(4))) float float4v;
typedef __attribute__((ext_vector_type(16))) float f32x16;
typedef __attribute__((ext_vector_type(2))) unsigned int uint2v;
typedef __attribute__((ext_vector_type(4))) unsigned int uint4v;

// cheap bf16 convert: round-half-up (bias ~2^-24 rel, negligible vs bf16 eps)
__device__ __forceinline__ unsigned short f2bf(float f) {
  return (unsigned short)((__builtin_bit_cast(unsigned int, f) + 0x8000u) >> 16);
}
// pack two floats -> two bf16 in one u32 via v_perm_b32 (3 VALU ops)
__device__ __forceinline__ unsigned int pkbf(float a, float b) {
  unsigned int ua = __builtin_bit_cast(unsigned int, a) + 0x8000u;
  unsigned int ub = __builtin_bit_cast(unsigned int, b) + 0x8000u;
  return __builtin_amdgcn_perm(ub, ua, 0x07060302u);  // {ub.hi16, ua.hi16}
}

__device__ __forceinline__ void async_copy16(const void* g, void* l) {
  __builtin_amdgcn_global_load_lds((__attribute__((address_space(1))) const void*)g,
                                   (__attribute__((address_space(3))) void*)l, 16, 0, 0);
}

// ---------------- cast X (fp32 -> bf16), 4 elems/thread ----------------
__global__ void cast_x_kernel(const float* __restrict__ X, unsigned short* __restrict__ Xb) {
  int i = blockIdx.x * blockDim.x + threadIdx.x;   // 0 .. 1048575
  float4 v = ((const float4*)X)[i];
  uint2 o;
  o.x = pkbf(v.x, v.y);
  o.y = pkbf(v.z, v.w);
  ((uint2*)Xb)[i] = o;
}

// ------------- transpose + cast weights: Wt[n][k] = bf16(W[k][n]) -------------
__global__ void trans_w_kernel(const float* __restrict__ W0, const float* __restrict__ W1,
                               const float* __restrict__ W2, const float* __restrict__ W3,
                               unsigned short* __restrict__ Wt) {
  __shared__ unsigned short tile[64][72];   // [n_loc][k_loc], padded
  const float* W = (blockIdx.z == 0) ? W0 : (blockIdx.z == 1) ? W1 : (blockIdx.z == 2) ? W2 : W3;
  unsigned short* out = Wt + (size_t)blockIdx.z * HDIM * HDIM;
  int n0 = blockIdx.x * 64, k0 = blockIdx.y * 64;
  int t = threadIdx.x;
#pragma unroll
  for (int it = 0; it < 4; ++it) {
    int idx = it * 256 + t;          // 1024 float4 chunks
    int r  = idx >> 4;               // k_loc 0..63
    int c4 = (idx & 15) * 4;         // n_loc
    float4 v = *(const float4*)&W[(size_t)(k0 + r) * HDIM + n0 + c4];
    tile[c4 + 0][r] = f2bf(v.x);
    tile[c4 + 1][r] = f2bf(v.y);
    tile[c4 + 2][r] = f2bf(v.z);
    tile[c4 + 3][r] = f2bf(v.w);
  }
  __syncthreads();
#pragma unroll
  for (int it = 0; it < 4; ++it) {
    int idx = it * 256 + t;
    int r  = idx >> 4;               // n_loc
    int c4 = (idx & 15) * 4;         // k_loc
    ushort4 o;
    o.x = tile[r][c4 + 0]; o.y = tile[r][c4 + 1];
    o.z = tile[r][c4 + 2]; o.w = tile[r][c4 + 3];
    *(ushort4*)&out[(size_t)(n0 + r) * HDIM + k0 + c4] = o;
  }
}

// ---------------- 128x128 bf16 MFMA GEMM, A(MxK) row-major, Bt(NxK) row-major ----------------
// mode 0: fp32 dense out[m*1024+n].
// mode 1: bf16; z==1 (K) -> (b,h,s,d) natural scatter;
//               z==0 (Q, pre-scaled by 0.125*log2e) and z==2 (V) -> (b,h,d,s) packed.
__global__ __launch_bounds__(256, 3) void gemm128_kernel(
    const unsigned short* __restrict__ A,
    const unsigned short* __restrict__ B0, const unsigned short* __restrict__ B1,
    const unsigned short* __restrict__ B2,
    void* __restrict__ outp, int mode)
{
  __shared__ unsigned short sA[128 * 32];
  __shared__ unsigned short sB[128 * 32];
  const int z = blockIdx.z;
  const unsigned short* Bt = (z == 0) ? B0 : (z == 1) ? B1 : B2;
  const int m0 = blockIdx.x * 128;
  const int n0 = blockIdx.y * 128;
  const int t = threadIdx.x;
  const int lane = t & 63;
  const int w = t >> 6;
  const int wm = w & 1, wn = w >> 1;

  const int sr  = lane >> 2;                  // row within 16
  const int scp = lane & 3;                   // physical chunk
  const int scl = scp ^ ((sr >> 1) & 3);      // logical (global) k-chunk
  const long ga0 = (long)(m0 + 16 * w + sr) * HDIM + scl * 8;
  const long ga1 = ga0 + 64l * HDIM;
  const long gb0 = (long)(n0 + 16 * w + sr) * HDIM + scl * 8;
  const long gb1 = gb0 + 64l * HDIM;
  unsigned short* lA0 = &sA[(16 * w) * 32];
  unsigned short* lA1 = &sA[(64 + 16 * w) * 32];
  unsigned short* lB0 = &sB[(16 * w) * 32];
  unsigned short* lB1 = &sB[(64 + 16 * w) * 32];

  const int fr = lane & 15;
  const int fq = lane >> 4;
  int offA[4], offB[4];
#pragma unroll
  for (int i = 0; i < 4; ++i) {
    int ra = wm * 64 + i * 16 + fr;
    offA[i] = ra * 32 + (fq ^ ((ra >> 1) & 3)) * 8;
    int rb = wn * 64 + i * 16 + fr;
    offB[i] = rb * 32 + (fq ^ ((rb >> 1) & 3)) * 8;
  }

  float4v acc[4][4] = {};

  for (int kk = 0; kk < HDIM; kk += 32) {
    __syncthreads();
    async_copy16(A + ga0 + kk, lA0);
    async_copy16(A + ga1 + kk, lA1);
    async_copy16(Bt + gb0 + kk, lB0);
    async_copy16(Bt + gb1 + kk, lB1);
    __syncthreads();
    short8 af[4], bf[4];
#pragma unroll
    for (int i = 0; i < 4; ++i) af[i] = *(const short8*)&sA[offA[i]];
#pragma unroll
    for (int i = 0; i < 4; ++i) bf[i] = *(const short8*)&sB[offB[i]];
#pragma unroll
    for (int mi = 0; mi < 4; ++mi)
#pragma unroll
      for (int ni = 0; ni < 4; ++ni)
        acc[mi][ni] = __builtin_amdgcn_mfma_f32_16x16x32_bf16(af[mi], bf[ni], acc[mi][ni], 0, 0, 0);
  }

  if (mode == 0) {
    float* out = (float*)outp;
#pragma unroll
    for (int mi = 0; mi < 4; ++mi)
#pragma unroll
      for (int ni = 0; ni < 4; ++ni)
#pragma unroll
        for (int rg = 0; rg < 4; ++rg) {
          int m = m0 + wm * 64 + mi * 16 + fq * 4 + rg;
          int n = n0 + wn * 64 + ni * 16 + fr;
          out[(size_t)m * HDIM + n] = acc[mi][ni][rg];
        }
  } else if (z != 1) {
    // transposed (b, h, d, s): 4 consecutive s per lane -> packed 8B stores.
    // z==0 (Q): fold softmax scale 0.125*log2(e) in here.
    const float scl = (z == 0) ? 0.18033688011112042f : 1.0f;
    unsigned short* out = (unsigned short*)outp + (size_t)z * QKV_STRIDE;
#pragma unroll
    for (int mi = 0; mi < 4; ++mi)
#pragma unroll
      for (int ni = 0; ni < 4; ++ni) {
        int m = m0 + wm * 64 + mi * 16 + fq * 4;   // s base (multiple of 4)
        int n = n0 + wn * 64 + ni * 16 + fr;
        int b = m >> 11, s = m & 2047, hh = n >> 6, d = n & 63;
        uint2 pk;
        pk.x = pkbf(acc[mi][ni][0] * scl, acc[mi][ni][1] * scl);
        pk.y = pkbf(acc[mi][ni][2] * scl, acc[mi][ni][3] * scl);
        *(uint2*)&out[(((size_t)(b * NHEADS + hh)) * HD + d) * S_LEN + s] = pk;
      }
  } else {
    unsigned short* out = (unsigned short*)outp + (size_t)z * QKV_STRIDE;
#pragma unroll
    for (int mi = 0; mi < 4; ++mi)
#pragma unroll
      for (int ni = 0; ni < 4; ++ni)
#pragma unroll
        for (int rg = 0; rg < 4; ++rg) {
          int m = m0 + wm * 64 + mi * 16 + fq * 4 + rg;
          int n = n0 + wn * 64 + ni * 16 + fr;
          int b = m >> 11, s = m & 2047, hh = n >> 6, d = n & 63;
          out[(((size_t)(b * NHEADS + hh)) * S_LEN + s) * HD + d] = f2bf(acc[mi][ni][rg]);
        }
  }
}

// stage one 64-k tile (K 8 KB + V^T 8 KB) into buffer (tile&1); 2 DMA copies per wave
__device__ __forceinline__ void stage_tile(char* smem, const unsigned short* Kp,
    const unsigned short* Vtp, size_t base, int tile, int w, int kr, int kc) {
  const int kv = tile * 64;
  char* bufb = smem + (tile & 1) * 16384;
  unsigned short* dK = (unsigned short*)bufb + (w * 8) * 64;
  async_copy16(Kp + base + (size_t)(kv + w * 8 + kr) * HD + ((kc ^ kr) * 8), dK);
  unsigned short* dV = (unsigned short*)(bufb + 8192) + (w * 8) * 64;
  const int d = w * 8 + kr;
  async_copy16(Vtp + base + (size_t)d * S_LEN + kv + ((kc ^ kr) * 8), dV);
}

// ---------------- flash attention: 32x32 swapped-QK^T, in-register softmax ----------------
// 8 waves = 4 q-groups x 2 k-halves; each wave owns a 32q x 32k strip per 64-k tile.
// S^T = mfma32x32x16(K, Q) in log2 domain (Q pre-scaled) -> lane holds 16 P values for
// q = lane&31 (k = (r&3)+8*(r>>2)+4*hi). P never touches LDS: v_cvt_pk_bf16_f32 pairs +
// 4x permlane32_swap rebuild the PV B-operand in registers (T12). Mask hoisted to a
// per-tile 64-lane ballot; all-ones fast path skips every per-element cndmask.
// K/V^T staging identical to previous version: dbuf 2x16KB, global_load_lds with
// pre-swizzled source, ONE barrier per tile (vmcnt drain covers prev-issued stage).
// LDS 34 KB: [0,32K) K/V dbuf; reduction record area (256 x 136 B) aliases it after
// the final barrier. kh-pair O/l merge + epilogue unchanged in structure.
__global__ __launch_bounds__(512, 4) void attn_kernel(
    const unsigned short* __restrict__ Qtp,
    const unsigned short* __restrict__ Kp,
    const unsigned short* __restrict__ Vtp,
    const int* __restrict__ mask,
    unsigned short* __restrict__ ctx)
{
  __shared__ __align__(16) char smem[34816];

  const int bh = blockIdx.y;
  const int b = bh >> 4;
  const int h = bh & 15;
  const size_t base = (size_t)bh * (S_LEN * HD);
  const int q0 = blockIdx.x * 128;
  const int t = threadIdx.x;
  const int lane = t & 63;
  const int w = t >> 6;                        // 0..7
  const int qg = w >> 1;                       // q-group (32 q)
  const int kh = w & 1;                        // k-half (32 k)
  const int ln = lane & 31;
  const int hi = lane >> 5;
  const int kr = lane >> 3, kc = lane & 7;     // staging lane map

  // Q B-fragments (32x32x16): step = 16-d block; lane holds Q[d=step*16+hi*8+j][q=ln]
  short8 qfr[4];
  const int sq = q0 + qg * 32 + ln;
#pragma unroll
  for (int st = 0; st < 4; ++st)
#pragma unroll
    for (int j = 0; j < 8; ++j)
      qfr[st][j] = (short)Qtp[base + (size_t)(st * 16 + hi * 8 + j) * S_LEN + sq];

  // LDS read offsets (element units); rows are XOR-swizzled in 16B chunks by the stager
  const int rk = kh * 32 + ln;                 // K row (A-operand row = lane&31)
  int offK[4];
#pragma unroll
  for (int st = 0; st < 4; ++st)
    offK[st] = rk * 64 + (((st * 2 + hi) ^ (rk & 7)) * 8);
  int offV[4];                                 // [dt*2+ks]
#pragma unroll
  for (int dt = 0; dt < 2; ++dt)
#pragma unroll
    for (int ks = 0; ks < 2; ++ks) {
      int rv = dt * 32 + ln;                   // V^T row (d)
      offV[dt * 2 + ks] = rv * 64 + (((kh * 4 + ks * 2 + hi) ^ (rv & 7)) * 8);
    }

  float l_lane = 0.f;
  f32x16 o_acc[2] = {};                        // O^T (64d x 32q), d split by dt/hi/reg

  // prologue: stage tile 0 into buffer 0
  stage_tile(smem, Kp, Vtp, base, 0, w, kr, kc);

#pragma unroll 2
  for (int it = 0; it < 32; ++it) {
    __syncthreads();   // drains vmcnt -> tile 'it' resident; buffer (it+1)&1 free
    if (it < 31)
      stage_tile(smem, Kp, Vtp, base, it + 1, w, kr, kc);   // in flight during compute

    const unsigned short* sKb  = (const unsigned short*)(smem + (it & 1) * 16384);
    const unsigned short* sVtb = (const unsigned short*)(smem + (it & 1) * 16384 + 8192);
    const int kv0 = it * 64;

    // per-tile mask ballot: bit k of bal = (mask[kv0+k] != 0)
    unsigned long long bal = __ballot(mask[b * S_LEN + kv0 + lane] != 0);

    // S^T (32k x 32q) = K · Q^T over this wave's strip, log2 domain
    f32x16 s_acc = {};
#pragma unroll
    for (int st = 0; st < 4; ++st) {
      short8 kf = *(const short8*)&sKb[offK[st]];
      s_acc = __builtin_amdgcn_mfma_f32_32x32x16_bf16(kf, qfr[st], s_acc, 0, 0, 0);
    }

    // exp2 -> (rare) mask zeroing -> l partials
    float p[16];
#pragma unroll
    for (int r = 0; r < 16; ++r) p[r] = __builtin_amdgcn_exp2f(s_acc[r]);
    if (bal != ~0ull) {                        // wave-uniform slow path
#pragma unroll
      for (int r = 0; r < 16; ++r) {
        unsigned bit = (unsigned)(bal >> (kh * 32 + 4 * hi + (r & 3) + 8 * (r >> 2))) & 1u;
        p[r] = bit ? p[r] : 0.f;
      }
    }
    {
      float a0 = (p[0] + p[1]) + (p[2] + p[3]);
      float a1 = (p[4] + p[5]) + (p[6] + p[7]);
      float a2 = (p[8] + p[9]) + (p[10] + p[11]);
      float a3 = (p[12] + p[13]) + (p[14] + p[15]);
      l_lane += (a0 + a1) + (a2 + a3);
    }

    // pack to bf16 pairs; w8[i] = {k = 8*(i>>1)+4hi+2*(i&1), +1}
    unsigned int w8[8];
#pragma unroll
    for (int i = 0; i < 8; ++i) {
      unsigned int r_;
      asm("v_cvt_pk_bf16_f32 %0, %1, %2" : "=v"(r_) : "v"(p[2 * i]), "v"(p[2 * i + 1]));
      w8[i] = r_;
    }
    // permlane32_swap(first.hi <-> second.lo): r[0] = {a.lo, b.lo^}, r[1] = {a.hi_v, b.hi}
    // -> B-fragment words k = hi*8 + {0..7} per 16-k step (guide T12 pairing w[i], w[i+2])
    uint2v s01 = __builtin_amdgcn_permlane32_swap(w8[0], w8[2], false, false);
    uint2v s23 = __builtin_amdgcn_permlane32_swap(w8[1], w8[3], false, false);
    uint2v s45 = __builtin_amdgcn_permlane32_swap(w8[4], w8[6], false, false);
    uint2v s67 = __builtin_amdgcn_permlane32_swap(w8[5], w8[7], false, false);
    uint4v f0 = {s01[0], s23[0], s01[1], s23[1]};
    uint4v f1 = {s45[0], s67[0], s45[1], s67[1]};
    short8 pf0 = __builtin_bit_cast(short8, f0);
    short8 pf1 = __builtin_bit_cast(short8, f1);

    // O^T += V^T · P^T (2 d-tiles x 2 k-steps)
#pragma unroll
    for (int dt = 0; dt < 2; ++dt) {
      short8 v0 = *(const short8*)&sVtb[offV[dt * 2 + 0]];
      short8 v1 = *(const short8*)&sVtb[offV[dt * 2 + 1]];
      o_acc[dt] = __builtin_amdgcn_mfma_f32_32x32x16_bf16(v0, pf0, o_acc[dt], 0, 0, 0);
      o_acc[dt] = __builtin_amdgcn_mfma_f32_32x32x16_bf16(v1, pf1, o_acc[dt], 0, 0, 0);
    }
  }

  // combine l across hi halves (each held half the k of this wave's strips)
  l_lane += __shfl_xor(l_lane, 32);

  // cross-wave-pair (kh) reduction via LDS: 32 O floats + l, stride 34 (136 B).
  // 4 pairs x 64 lanes x 136 B = 34816 B, aliasing the dead dbuf.
  __syncthreads();   // all waves done with buffers before aliasing
  float* red = (float*)smem;
  float* rec = red + (size_t)(qg * 64 + lane) * 34;
  if (kh) {
#pragma unroll
    for (int dt = 0; dt < 2; ++dt)
#pragma unroll
      for (int rp = 0; rp < 8; ++rp)
        *(float2*)&rec[dt * 16 + rp * 2] =
            make_float2(o_acc[dt][2 * rp], o_acc[dt][2 * rp + 1]);
    rec[32] = l_lane;
  }
  __syncthreads();
  if (!kh) {
#pragma unroll
    for (int dt = 0; dt < 2; ++dt)
#pragma unroll
      for (int rp = 0; rp < 8; ++rp) {
        float2 a = *(float2*)&rec[dt * 16 + rp * 2];
        o_acc[dt][2 * rp]     += a.x;
        o_acc[dt][2 * rp + 1] += a.y;
      }
    float inv_l = 1.0f / (l_lane + rec[32]);
    // epilogue: O^T lane layout -> 4 consecutive d per reg-quad -> packed 8B stores
    size_t rowoff = ((size_t)(b * S_LEN + sq)) * HDIM + h * HD;
#pragma unroll
    for (int dt = 0; dt < 2; ++dt)
#pragma unroll
      for (int g = 0; g < 4; ++g) {
        uint2 pk;
        pk.x = pkbf(o_acc[dt][4 * g]     * inv_l, o_acc[dt][4 * g + 1] * inv_l);
        pk.y = pkbf(o_acc[dt][4 * g + 2] * inv_l, o_acc[dt][4 * g + 3] * inv_l);
        *(uint2*)&ctx[rowoff + dt * 32 + g * 8 + hi * 4] = pk;
      }
  }
}

extern "C" void kernel_launch(void* const* d_in, const int* in_sizes, int n_in,
                              void* d_out, int out_size, void* d_ws, size_t ws_size,
                              hipStream_t stream) {
  const float* X  = (const float*)d_in[0];
  const int* mask = (const int*)d_in[1];
  const float* Wq = (const float*)d_in[2];
  const float* Wk = (const float*)d_in[3];
  const float* Wv = (const float*)d_in[4];
  const float* Wo = (const float*)d_in[5];
  float* out = (float*)d_out;

  char* ws = (char*)d_ws;
  // layout (40 MB): [0,8M) Xb then reused as CTX; [8M,16M) Wt x4; [16M,40M) Q^T,K,V^T bf16
  unsigned short* Xb  = (unsigned short*)(ws);
  unsigned short* Wt  = (unsigned short*)(ws + (8u << 20));
  unsigned short* QKV = (unsigned short*)(ws + (16u << 20));
  unsigned short* CTX = (unsigned short*)(ws);   // reuse Xb region (dead after QKV GEMM)

  cast_x_kernel<<<4096, 256, 0, stream>>>(X, Xb);
  trans_w_kernel<<<dim3(16, 16, 4), 256, 0, stream>>>(Wq, Wk, Wv, Wo, Wt);
  gemm128_kernel<<<dim3(32, 8, 3), 256, 0, stream>>>(
      Xb, Wt, Wt + (1u << 20), Wt + (2u << 20), QKV, 1);
  attn_kernel<<<dim3(16, 32), 512, 0, stream>>>(
      QKV, QKV + QKV_STRIDE, QKV + 2 * (size_t)QKV_STRIDE, mask, CTX);
  gemm128_kernel<<<dim3(32, 8, 1), 256, 0, stream>>>(
      CTX, Wt + (3u << 20), Wt + (3u << 20), Wt + (3u << 20), out, 0);
}

// Round 2
// 187.214 us; speedup vs baseline: 1.1522x; 1.1522x over previous
//
#include <hip/hip_runtime.h>
#include <hip/hip_bf16.h>

#define S_LEN 2048
#define HDIM  1024
#define NHEADS 16
#define HD    64
#define QKV_STRIDE (S_LEN * 2 * HDIM)   // 4194304 elements per tensor

typedef __attribute__((ext_vector_type(8))) short short8;
typedef __attribute__((ext_vector_type(4))) float float4v;

// cheap bf16 convert: round-half-up (bias ~2^-24 rel, negligible vs bf16 eps)
__device__ __forceinline__ unsigned short f2bf(float f) {
  return (unsigned short)((__builtin_bit_cast(unsigned int, f) + 0x8000u) >> 16);
}
// pack two floats -> two bf16 in one u32 via v_perm_b32 (3 VALU ops)
__device__ __forceinline__ unsigned int pkbf(float a, float b) {
  unsigned int ua = __builtin_bit_cast(unsigned int, a) + 0x8000u;
  unsigned int ub = __builtin_bit_cast(unsigned int, b) + 0x8000u;
  return __builtin_amdgcn_perm(ub, ua, 0x07060302u);  // {ub.hi16, ua.hi16}
}

__device__ __forceinline__ void async_copy16(const void* g, void* l) {
  __builtin_amdgcn_global_load_lds((__attribute__((address_space(1))) const void*)g,
                                   (__attribute__((address_space(3))) void*)l, 16, 0, 0);
}

// ---------------- cast X (fp32 -> bf16), 4 elems/thread ----------------
__global__ void cast_x_kernel(const float* __restrict__ X, unsigned short* __restrict__ Xb) {
  int i = blockIdx.x * blockDim.x + threadIdx.x;   // 0 .. 1048575
  float4 v = ((const float4*)X)[i];
  uint2 o;
  o.x = pkbf(v.x, v.y);
  o.y = pkbf(v.z, v.w);
  ((uint2*)Xb)[i] = o;
}

// ------------- transpose + cast weights: Wt[n][k] = bf16(W[k][n]) -------------
__global__ void trans_w_kernel(const float* __restrict__ W0, const float* __restrict__ W1,
                               const float* __restrict__ W2, const float* __restrict__ W3,
                               unsigned short* __restrict__ Wt) {
  __shared__ unsigned short tile[64][72];   // [n_loc][k_loc], padded
  const float* W = (blockIdx.z == 0) ? W0 : (blockIdx.z == 1) ? W1 : (blockIdx.z == 2) ? W2 : W3;
  unsigned short* out = Wt + (size_t)blockIdx.z * HDIM * HDIM;
  int n0 = blockIdx.x * 64, k0 = blockIdx.y * 64;
  int t = threadIdx.x;
#pragma unroll
  for (int it = 0; it < 4; ++it) {
    int idx = it * 256 + t;          // 1024 float4 chunks
    int r  = idx >> 4;               // k_loc 0..63
    int c4 = (idx & 15) * 4;         // n_loc
    float4 v = *(const float4*)&W[(size_t)(k0 + r) * HDIM + n0 + c4];
    tile[c4 + 0][r] = f2bf(v.x);
    tile[c4 + 1][r] = f2bf(v.y);
    tile[c4 + 2][r] = f2bf(v.z);
    tile[c4 + 3][r] = f2bf(v.w);
  }
  __syncthreads();
#pragma unroll
  for (int it = 0; it < 4; ++it) {
    int idx = it * 256 + t;
    int r  = idx >> 4;               // n_loc
    int c4 = (idx & 15) * 4;         // k_loc
    ushort4 o;
    o.x = tile[r][c4 + 0]; o.y = tile[r][c4 + 1];
    o.z = tile[r][c4 + 2]; o.w = tile[r][c4 + 3];
    *(ushort4*)&out[(size_t)(n0 + r) * HDIM + k0 + c4] = o;
  }
}

// ---------------- 128x128 bf16 MFMA GEMM, A(MxK) row-major, Bt(NxK) row-major ----------------
// mode 0: fp32 dense out[m*1024+n].
// mode 1: bf16; z==1 (K) -> (b,h,s,d) natural scatter;
//               z==0 (Q, pre-scaled by 0.125*log2e) and z==2 (V) -> (b,h,d,s) packed.
__global__ __launch_bounds__(256, 3) void gemm128_kernel(
    const unsigned short* __restrict__ A,
    const unsigned short* __restrict__ B0, const unsigned short* __restrict__ B1,
    const unsigned short* __restrict__ B2,
    void* __restrict__ outp, int mode)
{
  __shared__ unsigned short sA[128 * 32];
  __shared__ unsigned short sB[128 * 32];
  const int z = blockIdx.z;
  const unsigned short* Bt = (z == 0) ? B0 : (z == 1) ? B1 : B2;
  const int m0 = blockIdx.x * 128;
  const int n0 = blockIdx.y * 128;
  const int t = threadIdx.x;
  const int lane = t & 63;
  const int w = t >> 6;
  const int wm = w & 1, wn = w >> 1;

  const int sr  = lane >> 2;                  // row within 16
  const int scp = lane & 3;                   // physical chunk
  const int scl = scp ^ ((sr >> 1) & 3);      // logical (global) k-chunk
  const long ga0 = (long)(m0 + 16 * w + sr) * HDIM + scl * 8;
  const long ga1 = ga0 + 64l * HDIM;
  const long gb0 = (long)(n0 + 16 * w + sr) * HDIM + scl * 8;
  const long gb1 = gb0 + 64l * HDIM;
  unsigned short* lA0 = &sA[(16 * w) * 32];
  unsigned short* lA1 = &sA[(64 + 16 * w) * 32];
  unsigned short* lB0 = &sB[(16 * w) * 32];
  unsigned short* lB1 = &sB[(64 + 16 * w) * 32];

  const int fr = lane & 15;
  const int fq = lane >> 4;
  int offA[4], offB[4];
#pragma unroll
  for (int i = 0; i < 4; ++i) {
    int ra = wm * 64 + i * 16 + fr;
    offA[i] = ra * 32 + (fq ^ ((ra >> 1) & 3)) * 8;
    int rb = wn * 64 + i * 16 + fr;
    offB[i] = rb * 32 + (fq ^ ((rb >> 1) & 3)) * 8;
  }

  float4v acc[4][4] = {};

  for (int kk = 0; kk < HDIM; kk += 32) {
    __syncthreads();
    async_copy16(A + ga0 + kk, lA0);
    async_copy16(A + ga1 + kk, lA1);
    async_copy16(Bt + gb0 + kk, lB0);
    async_copy16(Bt + gb1 + kk, lB1);
    __syncthreads();
    short8 af[4], bf[4];
#pragma unroll
    for (int i = 0; i < 4; ++i) af[i] = *(const short8*)&sA[offA[i]];
#pragma unroll
    for (int i = 0; i < 4; ++i) bf[i] = *(const short8*)&sB[offB[i]];
#pragma unroll
    for (int mi = 0; mi < 4; ++mi)
#pragma unroll
      for (int ni = 0; ni < 4; ++ni)
        acc[mi][ni] = __builtin_amdgcn_mfma_f32_16x16x32_bf16(af[mi], bf[ni], acc[mi][ni], 0, 0, 0);
  }

  if (mode == 0) {
    float* out = (float*)outp;
#pragma unroll
    for (int mi = 0; mi < 4; ++mi)
#pragma unroll
      for (int ni = 0; ni < 4; ++ni)
#pragma unroll
        for (int rg = 0; rg < 4; ++rg) {
          int m = m0 + wm * 64 + mi * 16 + fq * 4 + rg;
          int n = n0 + wn * 64 + ni * 16 + fr;
          out[(size_t)m * HDIM + n] = acc[mi][ni][rg];
        }
  } else if (z != 1) {
    // transposed (b, h, d, s): 4 consecutive s per lane -> packed 8B stores.
    // z==0 (Q): fold softmax scale 0.125*log2(e) in here.
    const float scl = (z == 0) ? 0.18033688011112042f : 1.0f;
    unsigned short* out = (unsigned short*)outp + (size_t)z * QKV_STRIDE;
#pragma unroll
    for (int mi = 0; mi < 4; ++mi)
#pragma unroll
      for (int ni = 0; ni < 4; ++ni) {
        int m = m0 + wm * 64 + mi * 16 + fq * 4;   // s base (multiple of 4)
        int n = n0 + wn * 64 + ni * 16 + fr;
        int b = m >> 11, s = m & 2047, hh = n >> 6, d = n & 63;
        uint2 pk;
        pk.x = pkbf(acc[mi][ni][0] * scl, acc[mi][ni][1] * scl);
        pk.y = pkbf(acc[mi][ni][2] * scl, acc[mi][ni][3] * scl);
        *(uint2*)&out[(((size_t)(b * NHEADS + hh)) * HD + d) * S_LEN + s] = pk;
      }
  } else {
    unsigned short* out = (unsigned short*)outp + (size_t)z * QKV_STRIDE;
#pragma unroll
    for (int mi = 0; mi < 4; ++mi)
#pragma unroll
      for (int ni = 0; ni < 4; ++ni)
#pragma unroll
        for (int rg = 0; rg < 4; ++rg) {
          int m = m0 + wm * 64 + mi * 16 + fq * 4 + rg;
          int n = n0 + wn * 64 + ni * 16 + fr;
          int b = m >> 11, s = m & 2047, hh = n >> 6, d = n & 63;
          out[(((size_t)(b * NHEADS + hh)) * S_LEN + s) * HD + d] = f2bf(acc[mi][ni][rg]);
        }
  }
}

// stage one 64-k tile (K 8 KB + V^T 8 KB) into buffer (tile&1); 2 DMA copies per wave
__device__ __forceinline__ void stage_tile(char* smem, const unsigned short* Kp,
    const unsigned short* Vtp, size_t base, int tile, int w, int kr, int kc) {
  const int kv = tile * 64;
  char* bufb = smem + (tile & 1) * 16384;
  unsigned short* dK = (unsigned short*)bufb + (w * 8) * 64;
  async_copy16(Kp + base + (size_t)(kv + w * 8 + kr) * HD + ((kc ^ kr) * 8), dK);
  unsigned short* dV = (unsigned short*)(bufb + 8192) + (w * 8) * 64;
  const int d = w * 8 + kr;
  async_copy16(Vtp + base + (size_t)d * S_LEN + kv + ((kc ^ kr) * 8), dV);
}

// ---------------- flash attention: split-k waves, fixed-base softmax, ----------------
// ---------------- BN=64 double-buffered staging, ONE barrier per tile ----------------
// R0 structure restored (R1's 32x32 in-reg-softmax regressed: depth-4 MFMA chain +
// exp2/cvt/permlane serial path -> latency-bound, MfmaUtil 21->16, VALU 41->23).
// R2 deltas on top of R0:
//  (a) mask ballot, prefetched one tile ahead: 1x 4B load + __ballot + wave-uniform
//      branch replaces 2x int4 loads + 16 selects per tile (all-ones fast path).
//  (b) V ds_reads hoisted above the exp2/pack/P-write block: their ~120cy LDS latency
//      overlaps softmax VALU instead of stacking onto the P round-trip wait.
// 8 waves = 4 q-groups x 2 k-halves (32 q x 32 k each). Fixed-base softmax keeps the
// k-split linear; O/l partials merged across wave pairs once at the end via LDS.
// LDS 52 KB: [0,32K) K/V dbuf, [32K,52K) per-wave P strips (32 rows x 80 B).
__global__ __launch_bounds__(512, 4) void attn_kernel(
    const unsigned short* __restrict__ Qtp,
    const unsigned short* __restrict__ Kp,
    const unsigned short* __restrict__ Vtp,
    const int* __restrict__ mask,
    unsigned short* __restrict__ ctx)
{
  __shared__ __align__(16) char smem[53248];

  const int bh = blockIdx.y;
  const int b = bh >> 4;
  const int h = bh & 15;
  const size_t base = (size_t)bh * (S_LEN * HD);
  const int q0 = blockIdx.x * 128;
  const int t = threadIdx.x;
  const int lane = t & 63;
  const int w = t >> 6;                        // 0..7
  const int qg = w >> 1;                       // q-group (32 q)
  const int kh = w & 1;                        // k-half (32 k)
  const int fr = lane & 15;
  const int fq = lane >> 4;
  const int kr = lane >> 3, kc = lane & 7;     // staging lane map
  unsigned short* sPw = (unsigned short*)(smem + 32768) + w * (32 * 40);

  // Q fragments (B-operand): 32 q rows, from transposed (b,h,d,s) layout
  short8 qfr[2][2];
#pragma unroll
  for (int q_ = 0; q_ < 2; ++q_)
#pragma unroll
    for (int ks = 0; ks < 2; ++ks)
#pragma unroll
      for (int j = 0; j < 8; ++j)
        qfr[q_][ks][j] = (short)Qtp[base + (size_t)(ks * 32 + fq * 8 + j) * S_LEN
                                    + (q0 + qg * 32 + q_ * 16 + fr)];

  float l_lane[2] = {0.f, 0.f};
  float4v o_acc[4][2] = {};                    // [df][q_], partial O^T over this k-half
  const float4v zero4 = {0.f, 0.f, 0.f, 0.f};

  // mask prefetch for tile 0 (bit k of ballot = mask[kv0+k] != 0)
  int mnext = mask[b * S_LEN + lane];

  // prologue: stage tile 0 into buffer 0
  stage_tile(smem, Kp, Vtp, base, 0, w, kr, kc);

#pragma unroll 2
  for (int it = 0; it < 32; ++it) {
    __syncthreads();   // drains vmcnt -> tile 'it' resident; buffer (it+1)&1 free
    if (it < 31)
      stage_tile(smem, Kp, Vtp, base, it + 1, w, kr, kc);   // in flight during compute

    unsigned long long bal = __ballot(mnext != 0);
    if (it < 31)
      mnext = mask[b * S_LEN + (it + 1) * 64 + lane];       // prefetch next tile's mask

    const unsigned short* sKb  = (const unsigned short*)(smem + (it & 1) * 16384);
    const unsigned short* sVtb = (const unsigned short*)(smem + (it & 1) * 16384 + 8192);

    // S^T = K · Q^T over this wave's 32-k strip (scores in log2 domain: Q pre-scaled)
    float4v s_acc[2][2];
#pragma unroll
    for (int kf = 0; kf < 2; ++kf) {
      int rk = kh * 32 + kf * 16 + fr;
      short8 k0 = *(const short8*)&sKb[rk * 64 + ((fq ^ (rk & 7)) * 8)];
      short8 k1 = *(const short8*)&sKb[rk * 64 + (((4 + fq) ^ (rk & 7)) * 8)];
#pragma unroll
      for (int q_ = 0; q_ < 2; ++q_) {
        float4v s = __builtin_amdgcn_mfma_f32_16x16x32_bf16(k0, qfr[q_][0], zero4, 0, 0, 0);
        s_acc[kf][q_] = __builtin_amdgcn_mfma_f32_16x16x32_bf16(k1, qfr[q_][1], s, 0, 0, 0);
      }
    }

    // V fragments early: LDS latency overlaps the softmax VALU below
    short8 vf[4];
#pragma unroll
    for (int df = 0; df < 4; ++df) {
      int rv = df * 16 + fr;
      vf[df] = *(const short8*)&sVtb[rv * 64 + (((kh * 4 + fq) ^ (fr & 7)) * 8)];
    }

    // exp2 -> (rare) mask zeroing -> pack P^T strip -> per-lane l partials
#pragma unroll
    for (int kf = 0; kf < 2; ++kf) {
      unsigned mseg = 0xFu;
      if (bal != ~0ull)                        // wave-uniform slow path
        mseg = (unsigned)(bal >> (kh * 32 + kf * 16 + fq * 4)) & 0xFu;
#pragma unroll
      for (int q_ = 0; q_ < 2; ++q_) {
        float p0 = __builtin_amdgcn_exp2f(s_acc[kf][q_][0]);
        float p1 = __builtin_amdgcn_exp2f(s_acc[kf][q_][1]);
        float p2 = __builtin_amdgcn_exp2f(s_acc[kf][q_][2]);
        float p3 = __builtin_amdgcn_exp2f(s_acc[kf][q_][3]);
        if (bal != ~0ull) {
          p0 = (mseg & 1u) ? p0 : 0.f;
          p1 = (mseg & 2u) ? p1 : 0.f;
          p2 = (mseg & 4u) ? p2 : 0.f;
          p3 = (mseg & 8u) ? p3 : 0.f;
        }
        l_lane[q_] += (p0 + p1) + (p2 + p3);
        uint2 pk;
        pk.x = pkbf(p0, p1);
        pk.y = pkbf(p2, p3);
        *(uint2*)&sPw[(q_ * 16 + fr) * 40 + (kf * 4 + fq) * 4] = pk;
      }
    }
    // no barrier: sP strip is per-wave; LDS ops are in-order within a wave

    // O^T += V^T · P^T over this wave's 32-k strip (single k-step)
    short8 pf[2];
#pragma unroll
    for (int q_ = 0; q_ < 2; ++q_)
      pf[q_] = *(const short8*)&sPw[(q_ * 16 + fr) * 40 + fq * 8];
#pragma unroll
    for (int df = 0; df < 4; ++df)
#pragma unroll
      for (int q_ = 0; q_ < 2; ++q_)
        o_acc[df][q_] = __builtin_amdgcn_mfma_f32_16x16x32_bf16(vf[df], pf[q_], o_acc[df][q_], 0, 0, 0);
  }

  // reduce l over fq within the wave
#pragma unroll
  for (int q_ = 0; q_ < 2; ++q_) {
    l_lane[q_] += __shfl_xor(l_lane[q_], 16);
    l_lane[q_] += __shfl_xor(l_lane[q_], 32);
  }

  // cross-wave-pair (kh) reduction via LDS.
  // Record: 32 O floats + 2 l floats, stride 34 (136 B). 4 pairs x 64 lanes x 136 B
  // = 34816 B, aliasing the dbuf + wave-0's P strip (all dead after the barrier).
  __syncthreads();   // all waves done with buffers/strips before aliasing
  float* red = (float*)smem;
  float* rec = red + (size_t)(qg * 64 + lane) * 34;
  if (kh) {
#pragma unroll
    for (int df = 0; df < 4; ++df)
#pragma unroll
      for (int q_ = 0; q_ < 2; ++q_) {
        int e = df * 2 + q_;
        *(float2*)&rec[4 * e]     = make_float2(o_acc[df][q_][0], o_acc[df][q_][1]);
        *(float2*)&rec[4 * e + 2] = make_float2(o_acc[df][q_][2], o_acc[df][q_][3]);
      }
    *(float2*)&rec[32] = make_float2(l_lane[0], l_lane[1]);
  }
  __syncthreads();
  if (!kh) {
#pragma unroll
    for (int df = 0; df < 4; ++df)
#pragma unroll
      for (int q_ = 0; q_ < 2; ++q_) {
        int e = df * 2 + q_;
        float2 a = *(float2*)&rec[4 * e];
        float2 c = *(float2*)&rec[4 * e + 2];
        o_acc[df][q_][0] += a.x; o_acc[df][q_][1] += a.y;
        o_acc[df][q_][2] += c.x; o_acc[df][q_][3] += c.y;
      }
    float2 lr = *(float2*)&rec[32];
    float inv_l[2];
    inv_l[0] = 1.0f / (l_lane[0] + lr.x);
    inv_l[1] = 1.0f / (l_lane[1] + lr.y);
    // epilogue: O^T C-layout -> 4 consecutive d per lane -> packed 8B stores
#pragma unroll
    for (int q_ = 0; q_ < 2; ++q_) {
      size_t rowoff = ((size_t)(b * S_LEN + q0 + qg * 32 + q_ * 16 + fr)) * HDIM + h * HD;
#pragma unroll
      for (int df = 0; df < 4; ++df) {
        uint2 pk;
        pk.x = pkbf(o_acc[df][q_][0] * inv_l[q_], o_acc[df][q_][1] * inv_l[q_]);
        pk.y = pkbf(o_acc[df][q_][2] * inv_l[q_], o_acc[df][q_][3] * inv_l[q_]);
        *(uint2*)&ctx[rowoff + df * 16 + fq * 4] = pk;
      }
    }
  }
}

extern "C" void kernel_launch(void* const* d_in, const int* in_sizes, int n_in,
                              void* d_out, int out_size, void* d_ws, size_t ws_size,
                              hipStream_t stream) {
  const float* X  = (const float*)d_in[0];
  const int* mask = (const int*)d_in[1];
  const float* Wq = (const float*)d_in[2];
  const float* Wk = (const float*)d_in[3];
  const float* Wv = (const float*)d_in[4];
  const float* Wo = (const float*)d_in[5];
  float* out = (float*)d_out;

  char* ws = (char*)d_ws;
  // layout (40 MB): [0,8M) Xb then reused as CTX; [8M,16M) Wt x4; [16M,40M) Q^T,K,V^T bf16
  unsigned short* Xb  = (unsigned short*)(ws);
  unsigned short* Wt  = (unsigned short*)(ws + (8u << 20));
  unsigned short* QKV = (unsigned short*)(ws + (16u << 20));
  unsigned short* CTX = (unsigned short*)(ws);   // reuse Xb region (dead after QKV GEMM)

  cast_x_kernel<<<4096, 256, 0, stream>>>(X, Xb);
  trans_w_kernel<<<dim3(16, 16, 4), 256, 0, stream>>>(Wq, Wk, Wv, Wo, Wt);
  gemm128_kernel<<<dim3(32, 8, 3), 256, 0, stream>>>(
      Xb, Wt, Wt + (1u << 20), Wt + (2u << 20), QKV, 1);
  attn_kernel<<<dim3(16, 32), 512, 0, stream>>>(
      QKV, QKV + QKV_STRIDE, QKV + 2 * (size_t)QKV_STRIDE, mask, CTX);
  gemm128_kernel<<<dim3(32, 8, 1), 256, 0, stream>>>(
      CTX, Wt + (3u << 20), Wt + (3u << 20), Wt + (3u << 20), out, 0);
}